// Round 1
// baseline (4901.098 us; speedup 1.0000x reference)
//
#include <hip/hip_runtime.h>

// MambaSWELU forward on MI355X.
// Structure: embed -> 4x {rmsnorm, in_proj GEMM, conv+swelu, x_proj GEMM,
// dt GEMM(+softplus), fused selective scan (+Dskip+z-gate), out_proj GEMM(+resid)}
// -> 3x MLP GEMM(+swelu) -> logits GEMM (NT vs tok_emb) -> log_softmax loss.
// All GEMMs: bf16 MFMA 16x16x32, fp32 accumulate, fp32 in/out (convert in staging).

typedef __attribute__((ext_vector_type(4))) float f32x4;
typedef __attribute__((ext_vector_type(8))) short bf16x8;

#define DEV static __device__ __forceinline__

DEV unsigned short f2bf(float f) {
  union { float f; unsigned u; } v; v.f = f;
  unsigned u = v.u;
  unsigned r = u + 0x7FFFu + ((u >> 16) & 1u);   // round-to-nearest-even
  return (unsigned short)(r >> 16);
}

DEV float sigmoidf_(float x) { return 1.f / (1.f + __expf(-x)); }

// ---------------- embed: x = tok_emb[ids] + pos_emb[:S] ----------------
__global__ void k_embed(const float* __restrict__ tok, const float* __restrict__ pos,
                        const int* __restrict__ ids, float* __restrict__ x) {
  int i = blockIdx.x;            // row 0..1023 (b*512+t)
  int d = threadIdx.x * 4;
  int t = i & 511;
  int tk = ids[i];
  float4 a = *(const float4*)(tok + (size_t)tk * 1024 + d);
  float4 p = *(const float4*)(pos + (size_t)t * 1024 + d);
  float4 r = make_float4(a.x + p.x, a.y + p.y, a.z + p.z, a.w + p.w);
  *(float4*)(x + (size_t)i * 1024 + d) = r;
}

// ---------------- rmsnorm (row length 1024) ----------------
__global__ void k_rmsnorm(const float* __restrict__ x, const float* __restrict__ w,
                          float* __restrict__ h) {
  int i = blockIdx.x, tid = threadIdx.x;
  float4 v = *(const float4*)(x + (size_t)i * 1024 + tid * 4);
  float ss = v.x * v.x + v.y * v.y + v.z * v.z + v.w * v.w;
  #pragma unroll
  for (int off = 32; off; off >>= 1) ss += __shfl_down(ss, off);
  __shared__ float ps[4];
  if ((tid & 63) == 0) ps[tid >> 6] = ss;
  __syncthreads();
  float tot = ps[0] + ps[1] + ps[2] + ps[3];
  float sc = rsqrtf(tot * (1.0f / 1024.0f) + 1e-5f);
  float4 wv = *(const float4*)(w + tid * 4);
  float4 r = make_float4(v.x * sc * wv.x, v.y * sc * wv.y, v.z * sc * wv.z, v.w * sc * wv.w);
  *(float4*)(h + (size_t)i * 1024 + tid * 4) = r;
}

// ---------------- transpose: in[K][N] -> out[N][K], K,N multiples of 32 ----------------
__global__ void k_transpose(const float* __restrict__ in, float* __restrict__ out,
                            int K, int N) {
  __shared__ float tile[32][33];
  int n0 = blockIdx.x * 32, k0 = blockIdx.y * 32;
  int tx = threadIdx.x, ty = threadIdx.y;   // (32, 8)
  #pragma unroll
  for (int i = 0; i < 4; ++i)
    tile[ty + i * 8][tx] = in[(size_t)(k0 + ty + i * 8) * N + n0 + tx];
  __syncthreads();
  #pragma unroll
  for (int i = 0; i < 4; ++i)
    out[(size_t)(n0 + ty + i * 8) * K + k0 + tx] = tile[tx][ty + i * 8];
}

// ---------------- GEMM: C[M][N] = act(A[M][K] * Bt[N][K]^T + bias + resid) ----------------
// 128x128 tile, BK=32, 4 waves (2x2), each wave 64x64 via 4x4 mfma_16x16x32_bf16 frags.
// act: 0 none, 1 swelu(k), 2 softplus
__global__ __launch_bounds__(256)
void k_gemm(const float* __restrict__ A, int lda,
            const float* __restrict__ Bt, int ldb,
            float* C, int ldc,
            int M, int N, int K,
            const float* __restrict__ bias,
            const float* resid,
            int act, const float* __restrict__ kptr) {
  __shared__ __align__(16) unsigned short As[128][32];
  __shared__ __align__(16) unsigned short Bs[128][32];
  int tid = threadIdx.x;
  int bm = blockIdx.y, bn = blockIdx.x;
  int wid = tid >> 6, lane = tid & 63;
  int wm = wid & 1, wn = wid >> 1;
  int lr = lane & 15, lg = lane >> 4;

  f32x4 acc[4][4];
  #pragma unroll
  for (int mi = 0; mi < 4; ++mi)
    #pragma unroll
    for (int ni = 0; ni < 4; ++ni) acc[mi][ni] = {0.f, 0.f, 0.f, 0.f};

  int srow = tid >> 3;          // 0..31, +32 per pass
  int scol = (tid & 7) * 4;     // 0..28

  for (int k0 = 0; k0 < K; k0 += 32) {
    __syncthreads();
    #pragma unroll
    for (int p = 0; p < 4; ++p) {
      int r = srow + p * 32;
      float4 va = *(const float4*)(A + (size_t)(bm * 128 + r) * lda + k0 + scol);
      ushort4 pa = make_ushort4(f2bf(va.x), f2bf(va.y), f2bf(va.z), f2bf(va.w));
      *(ushort4*)&As[r][scol] = pa;
      int n = bn * 128 + r;
      float4 vb = make_float4(0.f, 0.f, 0.f, 0.f);
      if (n < N) vb = *(const float4*)(Bt + (size_t)n * ldb + k0 + scol);
      ushort4 pb = make_ushort4(f2bf(vb.x), f2bf(vb.y), f2bf(vb.z), f2bf(vb.w));
      *(ushort4*)&Bs[r][scol] = pb;
    }
    __syncthreads();
    bf16x8 af[4], bf[4];
    #pragma unroll
    for (int mi = 0; mi < 4; ++mi)
      af[mi] = *(const bf16x8*)&As[wm * 64 + mi * 16 + lr][lg * 8];
    #pragma unroll
    for (int ni = 0; ni < 4; ++ni)
      bf[ni] = *(const bf16x8*)&Bs[wn * 64 + ni * 16 + lr][lg * 8];
    #pragma unroll
    for (int mi = 0; mi < 4; ++mi)
      #pragma unroll
      for (int ni = 0; ni < 4; ++ni)
        acc[mi][ni] = __builtin_amdgcn_mfma_f32_16x16x32_bf16(af[mi], bf[ni], acc[mi][ni], 0, 0, 0);
  }

  float kact = kptr ? *kptr : 0.f;
  #pragma unroll
  for (int mi = 0; mi < 4; ++mi) {
    #pragma unroll
    for (int ni = 0; ni < 4; ++ni) {
      int col = bn * 128 + wn * 64 + ni * 16 + lr;
      if (col >= N) continue;
      float bv = bias ? bias[col] : 0.f;
      int row0 = bm * 128 + wm * 64 + mi * 16 + lg * 4;
      #pragma unroll
      for (int r = 0; r < 4; ++r) {
        float v = acc[mi][ni][r] + bv;
        size_t idx = (size_t)(row0 + r) * ldc + col;
        if (resid) v += resid[idx];
        if (act == 1) v = v * sigmoidf_(kact * v);
        else if (act == 2) v = (v > 20.f) ? v : log1pf(__expf(v));
        C[idx] = v;
      }
    }
  }
}

// ---------------- depthwise causal conv (KC=4) + swelu -> u2 ----------------
__global__ void k_conv(const float* __restrict__ xz, const float* __restrict__ cw,
                       const float* __restrict__ cb, const float* __restrict__ kp,
                       float* __restrict__ u2) {
  int idx = blockIdx.x * 256 + threadIdx.x;   // < 2*512*2048
  int d = idx & 2047;
  int r = idx >> 11;       // b*512 + t
  int t = r & 511, b = r >> 9;
  float acc = cb[d];
  const float* w = cw + (size_t)d * 4;
  #pragma unroll
  for (int k = 0; k < 4; ++k) {
    int ts = t + k - 3;
    if (ts >= 0) acc += xz[(size_t)((b << 9) + ts) * 4096 + d] * w[k];
  }
  float kb = *kp;
  u2[idx] = acc * sigmoidf_(kb * acc);
}

// ---------------- fused selective scan + D_skip + z-gate ----------------
// y[r,d] = (scan_y + Dskip[d]*u2) * swelu(z)
__global__ __launch_bounds__(256)
void k_scan(const float* __restrict__ dt, const float* __restrict__ u2,
            const float* __restrict__ xdbl, const float* __restrict__ xz,
            const float* __restrict__ Alog, const float* __restrict__ Dsk,
            const float* __restrict__ kp, float* __restrict__ y) {
  int tid = threadIdx.x;
  int d = (blockIdx.x & 7) * 256 + tid;
  int b = blockIdx.x >> 3;
  float A[16], h[16];
  #pragma unroll
  for (int n = 0; n < 16; ++n) { A[n] = -__expf(Alog[(size_t)d * 16 + n]); h[n] = 0.f; }
  float Dv = Dsk[d];
  float kb = *kp;
  __shared__ float sBC[64][32];   // Bm(16) | Cm(16) for a 64-step t-chunk
  for (int tc = 0; tc < 512; tc += 64) {
    __syncthreads();
    for (int i = tid; i < 64 * 32; i += 256) {
      int tt = i >> 5, j = i & 31;
      sBC[tt][j] = xdbl[(size_t)((b << 9) + tc + tt) * 96 + 64 + j];
    }
    __syncthreads();
    for (int tt = 0; tt < 64; ++tt) {
      int r = (b << 9) + tc + tt;
      float dtv = dt[(size_t)r * 2048 + d];
      float uv = u2[(size_t)r * 2048 + d];
      float du = dtv * uv;
      float yv = 0.f;
      #pragma unroll
      for (int n = 0; n < 16; ++n) {
        float dA = __expf(dtv * A[n]);
        h[n] = dA * h[n] + du * sBC[tt][n];
        yv += h[n] * sBC[tt][16 + n];
      }
      float z = xz[(size_t)r * 4096 + 2048 + d];
      float g = z * sigmoidf_(kb * z);
      y[(size_t)r * 2048 + d] = (yv + Dv * uv) * g;
    }
  }
}

// ---------------- loss: per-row logsumexp + nll ----------------
__global__ __launch_bounds__(256)
void k_loss_rows(const float* __restrict__ logits, const int* __restrict__ labels,
                 float* __restrict__ nll) {
  int bidx = blockIdx.x;                // 0..1021
  int b = bidx / 511, t = bidx % 511;
  int row = b * 512 + t;
  const float* lr = logits + (size_t)row * 50257;
  int lab = labels[b * 512 + t + 1];
  int tid = threadIdx.x;
  float m = -3.4e38f, s = 0.f;
  for (int v = tid; v < 50257; v += 256) {
    float xv = lr[v];
    if (xv > m) { s = s * __expf(m - xv) + 1.f; m = xv; }
    else s += __expf(xv - m);
  }
  __shared__ float sm[256], ssum[256];
  sm[tid] = m; ssum[tid] = s;
  __syncthreads();
  for (int off = 128; off; off >>= 1) {
    if (tid < off) {
      float m2 = sm[tid + off], s2 = ssum[tid + off];
      float M = fmaxf(sm[tid], m2);
      ssum[tid] = ssum[tid] * __expf(sm[tid] - M) + s2 * __expf(m2 - M);
      sm[tid] = M;
    }
    __syncthreads();
  }
  if (tid == 0) nll[bidx] = (sm[0] + logf(ssum[0])) - lr[lab];
}

__global__ void k_loss_final(const float* __restrict__ nll, float* __restrict__ out) {
  __shared__ float ps[256];
  int tid = threadIdx.x;
  float s = 0.f;
  for (int i = tid; i < 1022; i += 256) s += nll[i];
  ps[tid] = s;
  __syncthreads();
  for (int off = 128; off; off >>= 1) {
    if (tid < off) ps[tid] += ps[tid + off];
    __syncthreads();
  }
  if (tid == 0) out[0] = ps[0] * (1.0f / 1022.0f);
}

// ---------------- launch ----------------
extern "C" void kernel_launch(void* const* d_in, const int* in_sizes, int n_in,
                              void* d_out, int out_size, void* d_ws, size_t ws_size,
                              hipStream_t stream) {
  const float* tok_emb   = (const float*)d_in[0];
  const float* pos_emb   = (const float*)d_in[1];
  const float* norm_w    = (const float*)d_in[2];
  const float* in_proj_w = (const float*)d_in[3];
  const float* conv_w    = (const float*)d_in[4];
  const float* conv_b    = (const float*)d_in[5];
  const float* x_proj_w  = (const float*)d_in[6];
  const float* dt_proj_w = (const float*)d_in[7];
  const float* dt_proj_b = (const float*)d_in[8];
  const float* A_log     = (const float*)d_in[9];
  const float* D_skip    = (const float*)d_in[10];
  const float* out_proj_w= (const float*)d_in[11];
  const float* k_block   = (const float*)d_in[12];
  const float* d1_w      = (const float*)d_in[13];
  const float* d1_b      = (const float*)d_in[14];
  const float* d2_w      = (const float*)d_in[15];
  const float* d2_b      = (const float*)d_in[16];
  const float* d3_w      = (const float*)d_in[17];
  const float* d3_b      = (const float*)d_in[18];
  const float* sw_ks     = (const float*)d_in[19];
  const int*   ids       = (const int*)d_in[20];
  const int*   labels    = (const int*)d_in[21];
  float* out = (float*)d_out;

  float* ws = (float*)d_ws;
  const size_t MB = 1u << 20;   // floats
  float* x    = ws;                    // 1M
  float* h    = ws + 1 * MB;           // 1M
  float* xz   = ws + 2 * MB;           // 4M
  float* u2   = ws + 6 * MB;           // 2M
  float* dtb  = ws + 8 * MB;           // 2M
  float* y    = ws + 10 * MB;          // 2M
  float* xdbl = ws + 12 * MB;          // 128K
  float* wt   = ws + 12 * MB + (1u << 17);  // 4M (transposed-weight scratch)
  float* nll  = wt + 4 * MB;           // 1K

  dim3 tb(32, 8);

  k_embed<<<1024, 256, 0, stream>>>(tok_emb, pos_emb, ids, x);

  for (int l = 0; l < 4; ++l) {
    k_rmsnorm<<<1024, 256, 0, stream>>>(x, norm_w + l * 1024, h);
    // in_proj: [1024][4096]
    k_transpose<<<dim3(128, 32), tb, 0, stream>>>(in_proj_w + (size_t)l * 1024 * 4096, wt, 1024, 4096);
    k_gemm<<<dim3(32, 8), 256, 0, stream>>>(h, 1024, wt, 1024, xz, 4096,
                                            1024, 4096, 1024, nullptr, nullptr, 0, nullptr);
    k_conv<<<8192, 256, 0, stream>>>(xz, conv_w + (size_t)l * 2048 * 4, conv_b + l * 2048,
                                     k_block + l, u2);
    // x_proj: [1024][96]
    k_transpose<<<dim3(3, 64), tb, 0, stream>>>(x_proj_w + (size_t)l * 2048 * 96, wt, 2048, 96);
    k_gemm<<<dim3(1, 8), 256, 0, stream>>>(u2, 2048, wt, 2048, xdbl, 96,
                                           1024, 96, 2048, nullptr, nullptr, 0, nullptr);
    // dt: [1024][2048] = softplus(xdbl[:, :64] @ dt_proj_w + b)
    k_transpose<<<dim3(64, 2), tb, 0, stream>>>(dt_proj_w + (size_t)l * 64 * 2048, wt, 64, 2048);
    k_gemm<<<dim3(16, 8), 256, 0, stream>>>(xdbl, 96, wt, 64, dtb, 2048,
                                            1024, 2048, 64, dt_proj_b + l * 2048, nullptr, 2, nullptr);
    k_scan<<<16, 256, 0, stream>>>(dtb, u2, xdbl, xz, A_log + (size_t)l * 2048 * 16,
                                   D_skip + l * 2048, k_block + l, y);
    // out_proj: x += y @ [2048][1024]
    k_transpose<<<dim3(32, 64), tb, 0, stream>>>(out_proj_w + (size_t)l * 2048 * 1024, wt, 2048, 1024);
    k_gemm<<<dim3(8, 8), 256, 0, stream>>>(y, 2048, wt, 2048, x, 1024,
                                           1024, 1024, 2048, nullptr, x, 0, nullptr);
  }

  // MLP
  k_transpose<<<dim3(64, 32), tb, 0, stream>>>(d1_w, wt, 1024, 2048);
  k_gemm<<<dim3(16, 8), 256, 0, stream>>>(x, 1024, wt, 1024, y, 2048,
                                          1024, 2048, 1024, d1_b, nullptr, 1, sw_ks + 0);
  k_transpose<<<dim3(64, 64), tb, 0, stream>>>(d2_w, wt, 2048, 2048);
  k_gemm<<<dim3(16, 8), 256, 0, stream>>>(y, 2048, wt, 2048, dtb, 2048,
                                          1024, 2048, 2048, d2_b, nullptr, 1, sw_ks + 1);
  k_transpose<<<dim3(32, 64), tb, 0, stream>>>(d3_w, wt, 2048, 1024);
  k_gemm<<<dim3(8, 8), 256, 0, stream>>>(dtb, 2048, wt, 2048, u2, 1024,
                                         1024, 1024, 2048, d3_b, nullptr, 1, sw_ks + 2);

  // logits: [1024][50257] = x3 @ tok_emb^T  (tok_emb is already [N][K])
  k_gemm<<<dim3(393, 8), 256, 0, stream>>>(u2, 1024, tok_emb, 1024, out, 50257,
                                           1024, 50257, 1024, nullptr, nullptr, 0, nullptr);

  k_loss_rows<<<1022, 256, 0, stream>>>(out, labels, nll);
  k_loss_final<<<1, 256, 0, stream>>>(nll, out + (size_t)out_size - 1);
}